// Round 3
// baseline (224.042 us; speedup 1.0000x reference)
//
#include <hip/hip_runtime.h>
#include <hip/hip_cooperative_groups.h>
#include <math.h>
#include <stdint.h>

namespace cg = cooperative_groups;

#define NLAT 128
#define NLON 256
#define LMAX 50
#define MMAX 50
#define MGRID (NLAT*NLON)   // 32768
#define BATCH 2
#define NPTS 2048
#define NBKT 64
#define NSRT 2056           // 2048 points + 8 sentinels
#define PI_F 3.14159265358979323846f

typedef float v2f __attribute__((ext_vector_type(2)));

__device__ __forceinline__ uint32_t umin32(uint32_t a, uint32_t b) { return a < b ? a : b; }
__device__ __forceinline__ uint32_t umax32(uint32_t a, uint32_t b) { return a > b ? a : b; }

// ---- workspace layout (float offsets from d_ws) ----
#define WS_F    0                          // f[B][NLAT][NLON]            = 65536 floats
#define WS_SXY  65536                      // float2 sorted (phi,py)[B][NSRT]
#define WS_SR   (WS_SXY + BATCH*NSRT*2)    // float sorted rho[B][NSRT]
#define WS_BST  (WS_SR + BATCH*NSRT)       // int bucket-prefix[B][NBKT+1]
#define WS_WG   78080                      // float W[MMAX][LMAX][NLAT]   = 320000 floats
#define WS_CT   (WS_WG + MMAX*LMAX*NLAT)   // float ctab[MMAX][256]

// ============ single cooperative kernel: 256 blocks x 512 threads, 1 block/CU.
// Phase A: blocks 0..1 counting-sort; blocks 2..51 per-m tables.   grid.sync
// Phase B: every block = (b, jj): 3-NN for columns j=2jj, 2jj+1.   grid.sync
// Phase C: blocks 0..99 = (b, m): truncated DFT + Legendre contraction.
__global__ __launch_bounds__(512, 2)
void k_fused(const float* __restrict__ target, float* ws, float* out) {
    __shared__ __attribute__((aligned(16))) float2 s_all[NSRT];
    __shared__ float    s_rall[NSRT];
    __shared__ uint32_t s_keys[8*64*3];
    __shared__ int      cnt[NBKT], s_start[NBKT + 1], cur[NBKT];
    __shared__ int      s_win[2];
    __shared__ float    s_a[LMAX], s_bb[LMAX], s_w[NLAT];
    __shared__ float    s_cm;
    __shared__ float    red[NLAT*5];
    __shared__ float    sFre[NLAT];
    __shared__ float    cred[256];
    __shared__ float    ct_s[256];

    cg::grid_group grid = cg::this_grid();
    int blk = blockIdx.x;
    int tid = threadIdx.x;

    // ================= Phase A: shared precompute =================
    if (blk < BATCH) {
        // ---- counting sort for batch blk (bit-identical to r0 math)
        const float* tg = target + blk * NPTS * 3;
        if (tid < NBKT) cnt[tid] = 0;
        __syncthreads();
        float ph[4], py[4], rh[4]; int bk[4];
        #pragma unroll
        for (int c = 0; c < 4; ++c) {
            int p = tid + c * 512;
            float x = tg[p*3], y = tg[p*3+1], z = tg[p*3+2];
            float r = sqrtf(fmaf(x, x, fmaf(y, y, z*z)));
            float cc = fminf(1.f, fmaxf(-1.f, z / r));
            float pyv = acosf(cc) - PI_F;                   // [-pi, 0]
            ph[c] = atan2f(y, x); py[c] = pyv; rh[c] = r;
            int bb = (int)floorf((pyv + PI_F) * ((float)NBKT / PI_F));
            bk[c] = min(NBKT-1, max(0, bb));
            atomicAdd(&cnt[bk[c]], 1);
        }
        __syncthreads();
        if (tid < 64) {                                     // wave-0 prefix scan
            int v = cnt[tid];
            int cv = v;
            #pragma unroll
            for (int sh = 1; sh < 64; sh <<= 1) {
                int t = __shfl_up(v, sh);
                if (tid >= sh) v += t;
            }
            s_start[tid + 1] = v;
            cur[tid] = v - cv;
            if (tid == 0) s_start[0] = 0;
        }
        __syncthreads();
        #pragma unroll
        for (int c = 0; c < 4; ++c) {
            int pos = atomicAdd(&cur[bk[c]], 1);
            s_all[pos]  = make_float2(ph[c], py[c]);
            s_rall[pos] = rh[c];
        }
        if (tid < 8) {                                      // sentinels
            s_all[NPTS + tid] = make_float2(1e15f, 1e15f);
            s_rall[NPTS + tid] = 0.f;
        }
        __syncthreads();
        float2* gxy = (float2*)(ws + WS_SXY) + blk * NSRT;
        float*  gr  = ws + WS_SR + blk * NSRT;
        int*    bst = (int*)(ws + WS_BST) + blk * (NBKT + 1);
        for (int t = tid; t < NSRT; t += 512) { gxy[t] = s_all[t]; gr[t] = s_rall[t]; }
        if (tid <= NBKT) bst[tid] = s_start[tid];
    } else if (blk < BATCH + MMAX) {
        // ---- per-m tables (batch-independent)
        int m = blk - BATCH;
        if (tid < 64) {                                     // C(m) log-prefix product
            int i = tid;
            float v = (i >= 1 && i <= m)
                      ? 0.5f * __log2f((2.f*i + 1.f) / (2.f*i)) : 0.f;
            #pragma unroll
            for (int sh = 1; sh < 64; sh <<= 1) v += __shfl_xor(v, sh);
            if (i == 0) s_cm = ((m & 1) ? -1.f : 1.f) * exp2f(v);
        } else if (tid < 128) {                             // recurrence coeffs
            int l = tid - 64;
            if (l < LMAX) {
                float fl = (float)l, fm2 = (float)(m*m);
                s_a[l]  = sqrtf((4.f*fl*fl - 1.f) / fmaxf(fl*fl - fm2, 0.25f));
                float flm1 = fl - 1.f;
                s_bb[l] = sqrtf(fmaxf(flm1*flm1 - fm2, 0.f) /
                                fmaxf(4.f*flm1*flm1 - 1.f, 0.25f));
            }
        } else if (tid < 256) {                             // CC weights w(k)
            int k = tid - 128;
            float theta = (PI_F * (float)k) / 127.0f;
            float S = 0.0f;
            for (int kk = 1; kk <= 63; ++kk)
                S += 2.0f / (4.0f*kk*kk - 1.0f) * __cosf(2.0f * theta * (float)kk);
            float w = (2.0f/127.0f) * (1.0f - S);
            if (k == 0 || k == NLAT-1) w *= 0.5f;
            s_w[k] = w;
        } else {                                            // DFT cos table
            int j = tid - 256;
            ws[WS_CT + m*256 + j] =
                __cosf((float)((m * j) & 255) * (2.0f*PI_F/256.0f));
        }
        __syncthreads();
        if (tid < NLAT) {                                   // Legendre recurrence * w
            int k = tid;
            float* Wm = ws + WS_WG + m * (LMAX * NLAT);
            float theta = (PI_F * (float)k) / 127.0f;
            float x = __cosf(theta), sn = __sinf(theta);
            float w = s_w[k];
            float pmm;
            if (m == 0) pmm = 0.28209479177f;
            else {
                float mag = exp2f((float)m * __log2f(fabsf(sn)));
                float sg  = (sn < 0.f && (m & 1)) ? -1.f : 1.f;
                pmm = 0.28209479177f * s_cm * mag * sg;
            }
            for (int l = 0; l < m; ++l) Wm[l*NLAT + k] = 0.0f;
            float Plm2 = pmm;
            Wm[m*NLAT + k] = Plm2 * w;
            if (m + 1 < LMAX) {
                float Plm1 = sqrtf(2.0f*m + 3.0f) * x * pmm;
                Wm[(m+1)*NLAT + k] = Plm1 * w;
                for (int l = m + 2; l < LMAX; ++l) {
                    float P = s_a[l] * fmaf(-s_bb[l], Plm2, x * Plm1);
                    Wm[l*NLAT + k] = P * w;
                    Plm2 = Plm1; Plm1 = P;
                }
            }
        }
    }
    __threadfence();
    grid.sync();

    // ================= Phase B: windowed 3-NN, 2 columns per block =================
    {
        int b  = blk >> 7;
        int jj = blk & 127;
        if (tid <= NBKT)
            s_start[tid] = ((const int*)(ws + WS_BST))[b*(NBKT+1) + tid];
        __syncthreads();

        for (int cidx = 0; cidx < 2; ++cidx) {
            int j = jj * 2 + cidx;
            float gy = (float)(j - 128) * (PI_F / 128.0f);
            int c0 = (int)floorf((gy + PI_F) * ((float)NBKT / PI_F));
            c0 = min(NBKT-1, max(0, c0));
            if (tid < 64) {                                 // window ballot
                int t = tid;
                int lo_t = max(0, c0 - 5 - t), hi_t = min(NBKT-1, c0 + 5 + t);
                int cw_t = s_start[hi_t+1] - s_start[lo_t];
                unsigned long long ok =
                    __ballot(cw_t >= 192 || (lo_t == 0 && hi_t == NBKT-1));
                int t0 = __ffsll((unsigned long long)ok) - 1;
                if (tid == 0) {
                    s_win[0] = max(0, c0 - 5 - t0);
                    s_win[1] = min(NBKT-1, c0 + 5 + t0);
                }
            }
            __syncthreads();

            int lo = s_win[0], hi = s_win[1];
            int off0 = s_start[lo];
            int cw   = s_start[hi+1] - off0;                // 192..2048
            int n    = cw + 8;
            const float2* gxy = (const float2*)(ws + WS_SXY) + b * NSRT + off0;
            const float*  gr  = ws + WS_SR + b * NSRT + off0;
            for (int t = tid; t < n; t += 512) { s_all[t] = gxy[t]; s_rall[t] = gr[t]; }
            __syncthreads();

            // per-wave top-3 over its partition
            int q = ((cw + 3) / 4 + 1) & ~1;
            int lane = tid & 63;
            int wv   = tid >> 6;
            int part = wv & 3;
            int lat  = lane + ((wv >> 2) << 6);
            float gx = (float)lat * (PI_F / 128.0f);
            v2f gx2 = {gx, gx}, gy2 = {gy, gy};
            uint32_t k0 = ~0u, k1 = ~0u, k2 = ~0u;
            uint32_t nb = (uint32_t)(part * q);
            const float4* p4 = (const float4*)(s_all + part * q);
            int iters = q >> 1;
            #pragma unroll 4
            for (int i = 0; i < iters; ++i) {
                float4 Q = p4[i];                           // wave-uniform b128
                v2f px = {Q.x, Q.z}, pyy = {Q.y, Q.w};
                v2f dp = gx2 - px, dt = gy2 - pyy;
                v2f d = dp * dp;
                d = dt * dt + d;
                uint32_t key0 = (__float_as_uint(d.x) & 0xFFFFF800u) | (nb + 2u*i);
                uint32_t key1 = (__float_as_uint(d.y) & 0xFFFFF800u) | (nb + 2u*i + 1u);
                uint32_t t1;
                t1 = umin32(umax32(key0, k0), k1);
                k2 = umin32(umax32(key0, k1), k2);
                k0 = umin32(key0, k0); k1 = t1;
                t1 = umin32(umax32(key1, k0), k1);
                k2 = umin32(umax32(key1, k1), k2);
                k0 = umin32(key1, k0); k1 = t1;
            }
            s_keys[(wv*64 + lane)*3 + 0] = k0;
            s_keys[(wv*64 + lane)*3 + 1] = k1;
            s_keys[(wv*64 + lane)*3 + 2] = k2;
            __syncthreads();

            // merge partitions, weighted combine, write column
            if (tid < 128) {
                int lane2 = tid & 63;
                int half  = tid >> 6;
                uint32_t m0 = ~0u, m1 = ~0u, m2 = ~0u;
                #pragma unroll
                for (int w = half*4; w < half*4 + 4; ++w) {
                    #pragma unroll
                    for (int s = 0; s < 3; ++s) {
                        uint32_t key = s_keys[(w*64 + lane2)*3 + s];
                        uint32_t t1 = umin32(umax32(key, m0), m1);
                        m2 = umin32(umax32(key, m1), m2);
                        m0 = umin32(key, m0); m1 = t1;
                    }
                }
                int i0 = (int)(m0 & 2047);
                int i1 = (int)(m1 & 2047);
                int i2 = (int)(m2 & 2047);
                int lat2 = lane2 + (half << 6);
                float gxs = (float)lat2 * (PI_F / 128.0f);
                float2 p0 = s_all[i0], p1 = s_all[i1], p2 = s_all[i2];
                float e, r0, r1, r2;
                e = gxs - p0.x; r0 = e*e; e = gy - p0.y; r0 = sqrtf(fmaf(e, e, r0));
                e = gxs - p1.x; r1 = e*e; e = gy - p1.y; r1 = sqrtf(fmaf(e, e, r1));
                e = gxs - p2.x; r2 = e*e; e = gy - p2.y; r2 = sqrtf(fmaf(e, e, r2));
                float sum = r0 + r1 + r2;
                float interp = (s_rall[i0]*r0 + s_rall[i1]*r1 + s_rall[i2]*r2) / sum;
                ws[WS_F + b * MGRID + lat2 * NLON + j] = interp;
            }
            __syncthreads();                                // protect s_all/s_keys reuse
        }
    }
    __threadfence();
    grid.sync();

    // ================= Phase C: table-driven DFT + contraction =================
    if (blk >= BATCH * MMAX) return;
    {
        int b = blk / MMAX;
        int m = blk % MMAX;

        if (tid < 256) ct_s[tid] = ws[WS_CT + m*256 + tid];
        __syncthreads();

        // partial DFT: k = tid>>2 (row), g = tid&3 (quarter), 16 float4 each
        {
            int k = tid >> 2, g = tid & 3;
            const float4* fb4 = (const float4*)(ws + WS_F + b * MGRID);
            float p = 0.0f;
            int j0 = g * 64;
            #pragma unroll
            for (int i = 0; i < 16; ++i) {
                float4 v = fb4[k * 64 + g * 16 + i];        // j = 64g + 4i
                p = fmaf(v.x, ct_s[j0 + 4*i    ], p);
                p = fmaf(v.y, ct_s[j0 + 4*i + 1], p);
                p = fmaf(v.z, ct_s[j0 + 4*i + 2], p);
                p = fmaf(v.w, ct_s[j0 + 4*i + 3], p);
            }
            red[k * 5 + g] = p;
        }
        __syncthreads();

        if (tid < NLAT) {
            int k = tid;
            sFre[k] = (red[k*5] + red[k*5+1] + red[k*5+2] + red[k*5+3])
                      * (2.0f * PI_F / 256.0f);
        }
        __syncthreads();

        // contraction: out[b,l,m] = sum_k Wg[m][l][k] * sFre[k]
        float acc = 0.0f;
        if (tid < 200) {
            int l = tid >> 2, kq = tid & 3;
            const float* Wm = ws + WS_WG + (m * LMAX + l) * NLAT;
            #pragma unroll 8
            for (int i = 0; i < 32; ++i)
                acc = fmaf(Wm[kq*32 + i], sFre[kq*32 + i], acc);
        }
        if (tid < 256) cred[tid] = acc;
        __syncthreads();
        if (tid < LMAX)
            out[(b*LMAX + tid)*MMAX + m] =
                cred[4*tid] + cred[4*tid+1] + cred[4*tid+2] + cred[4*tid+3];
    }
}

extern "C" void kernel_launch(void* const* d_in, const int* in_sizes, int n_in,
                              void* d_out, int out_size, void* d_ws, size_t ws_size,
                              hipStream_t stream) {
    const float* target = (const float*)d_in[0];
    float* out = (float*)d_out;
    float* ws  = (float*)d_ws;

    void* args[] = { (void*)&target, (void*)&ws, (void*)&out };
    hipLaunchCooperativeKernel((void*)k_fused, dim3(256), dim3(512),
                               args, 0, stream);
}

// Round 4
// 73.525 us; speedup vs baseline: 3.0472x; 3.0472x over previous
//
#include <hip/hip_runtime.h>
#include <math.h>
#include <stdint.h>

#define NLAT 128
#define NLON 256
#define LMAX 50
#define MMAX 50
#define MGRID (NLAT*NLON)   // 32768
#define BATCH 2
#define NPTS 2048
#define NBKT 64
#define PI_F 3.14159265358979323846f

typedef float v2f __attribute__((ext_vector_type(2)));

__device__ __forceinline__ uint32_t umin32(uint32_t a, uint32_t b) { return a < b ? a : b; }
__device__ __forceinline__ uint32_t umax32(uint32_t a, uint32_t b) { return a > b ? a : b; }

// ---- workspace layout (float offsets from d_ws) ----
#define WS_F    0                          // f[B][NLAT][NLON] = 65536 floats
#define WS_WG   65536                      // float W[MMAX][LMAX][NLAT] = 320000 floats
#define WS_CT   (WS_WG + MMAX*LMAX*NLAT)   // float ctab[MMAX][256]

// ============ kernel 1: blocks 0..511 = r0's self-contained NN (sort+scan+combine);
// blocks 512..561 = per-m table gen (runs concurrently, hidden under NN wall time).
__global__ __launch_bounds__(512, 2)
void k_main(const float* __restrict__ target, float* __restrict__ ws) {
    __shared__ __attribute__((aligned(16))) float2 s_all[NPTS + 8];
    __shared__ float    s_rall[NPTS + 8];
    __shared__ uint32_t s_keys[8*64*3];
    __shared__ int      cnt[NBKT], start[NBKT + 1], cur[NBKT];
    __shared__ int      s_win[2];
    __shared__ float    s_a[LMAX], s_bb[LMAX], s_w[NLAT];
    __shared__ float    s_cm;
    int blk = blockIdx.x;
    int tid = threadIdx.x;

    if (blk >= 512) {
        // ---------- per-m tables (r2-verified k_prep else-branch) ----------
        int m = blk - 512;
        if (tid < 64) {                                     // C(m) log-prefix product
            int i = tid;
            float v = (i >= 1 && i <= m)
                      ? 0.5f * __log2f((2.f*i + 1.f) / (2.f*i)) : 0.f;
            #pragma unroll
            for (int sh = 1; sh < 64; sh <<= 1) v += __shfl_xor(v, sh);
            if (i == 0) s_cm = ((m & 1) ? -1.f : 1.f) * exp2f(v);
        } else if (tid < 128) {                             // recurrence coeffs
            int l = tid - 64;
            if (l < LMAX) {
                float fl = (float)l, fm2 = (float)(m*m);
                s_a[l]  = sqrtf((4.f*fl*fl - 1.f) / fmaxf(fl*fl - fm2, 0.25f));
                float flm1 = fl - 1.f;
                s_bb[l] = sqrtf(fmaxf(flm1*flm1 - fm2, 0.f) /
                                fmaxf(4.f*flm1*flm1 - 1.f, 0.25f));
            }
        } else if (tid < 256) {                             // CC weights w(k)
            int k = tid - 128;
            float theta = (PI_F * (float)k) / 127.0f;
            float S = 0.0f;
            for (int kk = 1; kk <= 63; ++kk)
                S += 2.0f / (4.0f*kk*kk - 1.0f) * __cosf(2.0f * theta * (float)kk);
            float w = (2.0f/127.0f) * (1.0f - S);
            if (k == 0 || k == NLAT-1) w *= 0.5f;
            s_w[k] = w;
        } else {                                            // DFT cos table
            int j = tid - 256;
            ws[WS_CT + m*256 + j] =
                __cosf((float)((m * j) & 255) * (2.0f*PI_F/256.0f));
        }
        __syncthreads();
        if (tid < NLAT) {                                   // Legendre recurrence * w
            int k = tid;
            float* Wm = ws + WS_WG + m * (LMAX * NLAT);
            float theta = (PI_F * (float)k) / 127.0f;
            float x = __cosf(theta), sn = __sinf(theta);
            float w = s_w[k];
            float pmm;
            if (m == 0) pmm = 0.28209479177f;
            else {
                float mag = exp2f((float)m * __log2f(fabsf(sn)));
                float sg  = (sn < 0.f && (m & 1)) ? -1.f : 1.f;
                pmm = 0.28209479177f * s_cm * mag * sg;
            }
            for (int l = 0; l < m; ++l) Wm[l*NLAT + k] = 0.0f;
            float Plm2 = pmm;
            Wm[m*NLAT + k] = Plm2 * w;
            if (m + 1 < LMAX) {
                float Plm1 = sqrtf(2.0f*m + 3.0f) * x * pmm;
                Wm[(m+1)*NLAT + k] = Plm1 * w;
                for (int l = m + 2; l < LMAX; ++l) {
                    float P = s_a[l] * fmaf(-s_bb[l], Plm2, x * Plm1);
                    Wm[l*NLAT + k] = P * w;
                    Plm2 = Plm1; Plm1 = P;
                }
            }
        }
        return;
    }

    // ---------- NN path: r0-verified self-contained block (b, j) ----------
    int b = blk >> 8;
    int j = blk & 255;
    const float* tg = target + b * NPTS * 3;

    // ---- phase 1: cart->sph (4 pts/thread) + bucket count
    if (tid < NBKT) cnt[tid] = 0;
    __syncthreads();
    float ph[4], py[4], rh[4]; int bk[4];
    #pragma unroll
    for (int c = 0; c < 4; ++c) {
        int p = tid + c * 512;
        float x = tg[p*3], y = tg[p*3+1], z = tg[p*3+2];
        float r = sqrtf(fmaf(x, x, fmaf(y, y, z*z)));
        float cc = fminf(1.f, fmaxf(-1.f, z / r));
        float pyv = acosf(cc) - PI_F;                       // [-pi, 0]
        ph[c] = atan2f(y, x); py[c] = pyv; rh[c] = r;
        int bb = (int)floorf((pyv + PI_F) * ((float)NBKT / PI_F));
        bk[c] = min(NBKT-1, max(0, bb));
        atomicAdd(&cnt[bk[c]], 1);
    }
    __syncthreads();

    // ---- phase 2a: wave-0 parallel prefix scan of bucket counts
    if (tid < 64) {
        int v = cnt[tid];
        int cv = v;
        #pragma unroll
        for (int sh = 1; sh < 64; sh <<= 1) {
            int t = __shfl_up(v, sh);
            if (tid >= sh) v += t;
        }
        start[tid + 1] = v;                                 // inclusive
        cur[tid] = v - cv;                                  // exclusive
        if (tid == 0) start[0] = 0;
    }
    __syncthreads();

    // ---- phase 2b: scatter into sorted order + sentinel pad; window ballot
    #pragma unroll
    for (int c = 0; c < 4; ++c) {
        int pos = atomicAdd(&cur[bk[c]], 1);
        s_all[pos]  = make_float2(ph[c], py[c]);
        s_rall[pos] = rh[c];
    }
    if (tid < 8) {
        s_all[NPTS + tid] = make_float2(1e15f, 1e15f);      // sentinel
        s_rall[NPTS + tid] = 0.f;
    }
    float gy = (float)(j - 128) * (PI_F / 128.0f);
    int c0 = (int)floorf((gy + PI_F) * ((float)NBKT / PI_F));
    c0 = min(NBKT-1, max(0, c0));
    if (tid < 64) {                                         // start[] final
        int t = tid;
        int lo_t = max(0, c0 - 5 - t), hi_t = min(NBKT-1, c0 + 5 + t);
        int cw_t = start[hi_t+1] - start[lo_t];
        unsigned long long ok =
            __ballot(cw_t >= 192 || (lo_t == 0 && hi_t == NBKT-1));
        int t0 = __ffsll((unsigned long long)ok) - 1;
        if (tid == 0) {
            s_win[0] = max(0, c0 - 5 - t0);
            s_win[1] = min(NBKT-1, c0 + 5 + t0);
        }
    }
    __syncthreads();

    // ---- phase 3: per-wave top-3 over its partition of the sorted window
    int lo = s_win[0], hi = s_win[1];
    int off = start[lo] & ~1;                               // even: float4 align
    int cw  = start[hi+1] - off;                            // <= 2048
    int q = ((cw + 3) / 4 + 1) & ~1;                        // even, 4q >= cw
    int lane = tid & 63;
    int wv   = tid >> 6;
    int part = wv & 3;
    int lat  = lane + ((wv >> 2) << 6);
    float gx = (float)lat * (PI_F / 128.0f);
    v2f gx2 = {gx, gx}, gy2 = {gy, gy};
    uint32_t k0 = ~0u, k1 = ~0u, k2 = ~0u;
    uint32_t nb = (uint32_t)(part * q);
    const float4* p4 = (const float4*)(s_all + off + part * q);
    int iters = q >> 1;
    #pragma unroll 4
    for (int i = 0; i < iters; ++i) {
        float4 Q = p4[i];                                   // wave-uniform b128
        v2f px = {Q.x, Q.z}, pyy = {Q.y, Q.w};
        v2f dp = gx2 - px, dt = gy2 - pyy;
        v2f d = dp * dp;
        d = dt * dt + d;
        uint32_t key0 = (__float_as_uint(d.x) & 0xFFFFF800u) | (nb + 2u*i);
        uint32_t key1 = (__float_as_uint(d.y) & 0xFFFFF800u) | (nb + 2u*i + 1u);
        uint32_t t1;
        t1 = umin32(umax32(key0, k0), k1);
        k2 = umin32(umax32(key0, k1), k2);
        k0 = umin32(key0, k0); k1 = t1;
        t1 = umin32(umax32(key1, k0), k1);
        k2 = umin32(umax32(key1, k1), k2);
        k0 = umin32(key1, k0); k1 = t1;
    }
    s_keys[(wv*64 + lane)*3 + 0] = k0;
    s_keys[(wv*64 + lane)*3 + 1] = k1;
    s_keys[(wv*64 + lane)*3 + 2] = k2;
    __syncthreads();

    // ---- phase 4: merge partitions, weighted combine, write column
    if (tid < 128) {
        int lane2 = tid & 63;
        int half  = tid >> 6;
        uint32_t m0 = ~0u, m1 = ~0u, m2 = ~0u;
        #pragma unroll
        for (int w = half*4; w < half*4 + 4; ++w) {
            #pragma unroll
            for (int s = 0; s < 3; ++s) {
                uint32_t key = s_keys[(w*64 + lane2)*3 + s];
                uint32_t t1 = umin32(umax32(key, m0), m1);
                m2 = umin32(umax32(key, m1), m2);
                m0 = umin32(key, m0); m1 = t1;
            }
        }
        int i0 = off + (int)(m0 & 2047);
        int i1 = off + (int)(m1 & 2047);
        int i2 = off + (int)(m2 & 2047);
        int lat2 = lane2 + (half << 6);
        float gxs = (float)lat2 * (PI_F / 128.0f);
        float2 p0 = s_all[i0], p1 = s_all[i1], p2 = s_all[i2];
        float e, r0, r1, r2;
        e = gxs - p0.x; r0 = e*e; e = gy - p0.y; r0 = sqrtf(fmaf(e, e, r0));
        e = gxs - p1.x; r1 = e*e; e = gy - p1.y; r1 = sqrtf(fmaf(e, e, r1));
        e = gxs - p2.x; r2 = e*e; e = gy - p2.y; r2 = sqrtf(fmaf(e, e, r2));
        float sum = r0 + r1 + r2;
        float interp = (s_rall[i0]*r0 + s_rall[i1]*r1 + s_rall[i2]*r2) / sum;
        ws[WS_F + b * MGRID + lat2 * NLON + j] = interp;
    }
}

// ============ kernel 2: table-driven truncated-DFT + Legendre contraction
// (r2-verified). One block per (b, m); pure fma phases.
__global__ __launch_bounds__(512)
void k_fft(const float* __restrict__ ws_c, float* __restrict__ out) {
    __shared__ float red[NLAT*5];
    __shared__ float sFre[NLAT];
    __shared__ float cred[256];
    __shared__ float ct_s[256];
    int b = blockIdx.x / MMAX;
    int m = blockIdx.x % MMAX;
    int tid = threadIdx.x;

    if (tid < 256) ct_s[tid] = ws_c[WS_CT + m*256 + tid];
    __syncthreads();

    // partial DFT: k = tid>>2 (row), g = tid&3 (quarter), 16 float4 each
    {
        int k = tid >> 2, g = tid & 3;
        const float4* fb4 = (const float4*)(ws_c + WS_F + b * MGRID);
        float p = 0.0f;
        int j0 = g * 64;
        #pragma unroll
        for (int i = 0; i < 16; ++i) {
            float4 v = fb4[k * 64 + g * 16 + i];            // j = 64g + 4i
            p = fmaf(v.x, ct_s[j0 + 4*i    ], p);
            p = fmaf(v.y, ct_s[j0 + 4*i + 1], p);
            p = fmaf(v.z, ct_s[j0 + 4*i + 2], p);
            p = fmaf(v.w, ct_s[j0 + 4*i + 3], p);
        }
        red[k * 5 + g] = p;
    }
    __syncthreads();

    if (tid < NLAT) {
        int k = tid;
        sFre[k] = (red[k*5] + red[k*5+1] + red[k*5+2] + red[k*5+3])
                  * (2.0f * PI_F / 256.0f);
    }
    __syncthreads();

    // contraction: out[b,l,m] = sum_k Wg[m][l][k] * sFre[k]
    float acc = 0.0f;
    if (tid < 200) {
        int l = tid >> 2, kq = tid & 3;
        const float* Wm = ws_c + WS_WG + (m * LMAX + l) * NLAT;
        #pragma unroll 8
        for (int i = 0; i < 32; ++i)
            acc = fmaf(Wm[kq*32 + i], sFre[kq*32 + i], acc);
    }
    if (tid < 256) cred[tid] = acc;
    __syncthreads();
    if (tid < LMAX)
        out[(b*LMAX + tid)*MMAX + m] =
            cred[4*tid] + cred[4*tid+1] + cred[4*tid+2] + cred[4*tid+3];
}

extern "C" void kernel_launch(void* const* d_in, const int* in_sizes, int n_in,
                              void* d_out, int out_size, void* d_ws, size_t ws_size,
                              hipStream_t stream) {
    const float* target = (const float*)d_in[0];
    float* out = (float*)d_out;
    float* ws  = (float*)d_ws;

    k_main<<<512 + MMAX, 512, 0, stream>>>(target, ws);     // NN + table blocks
    k_fft <<<BATCH * MMAX, 512, 0, stream>>>(ws, out);      // table-driven
}